// Round 10
// baseline (43578.464 us; speedup 1.0000x reference)
//
#include <hip/hip_runtime.h>
#include <hip/hip_bf16.h>

// 2-layer LSTM, B=64 T=2048 D=H=256, fp32 I/O.
// v10: j-split scan across WG PAIRS with per-step L2 flag exchange.
//   Round-8/9 evidence: per-WG scan is VALU/latency-bound at ~1.66us/step and
//   register-allocation heuristics block further IPC gains; only 128/256 CUs
//   used. Fix: each (job,b) -> 2 WGs, each owning 128 hidden units
//   (weights/thread: 23 VGPR + 9 LDS blocks at 512 thr). Per step each WG
//   publishes its h-half (256B) + release flag; partner threads (whose
//   k-range is the other half) spin-acquire and read. Parity double-buffer,
//   monotonic flags (zeroed each launch), __syncthreads+__threadfence+flag.
//   Co-residency by capacity: LDS 88.6KB -> exactly 1 WG/CU -> all 256 WGs
//   of a dual slot resident. Pairs (wg, wg^64) -> same XCD under round-robin.

typedef unsigned short u16;
typedef unsigned int   u32;

typedef __attribute__((ext_vector_type(8))) _Float16       half8;
typedef __attribute__((ext_vector_type(2))) _Float16       half2_t;
typedef __attribute__((ext_vector_type(8))) unsigned short ushort8;
typedef __attribute__((ext_vector_type(4))) float          f32x4;

#define B_  64
#define T_  2048
#define D_  256
#define H_  256
#define G_  1024   // 4*H

#define NRG 23     // scan: k2-blocks per thread in VGPRs
#define NLD 9      // scan: k2-blocks per thread in LDS (NRG+NLD = 32)
static_assert(NRG + NLD == 32, "k-split coverage");

// ---- helpers ----
__device__ __forceinline__ u16 f2h(float f) {
    union { _Float16 h; u16 b; } v; v.h = (_Float16)f; return v.b;
}
__device__ __forceinline__ float dot2(u32 w, u32 hv, float acc) {
#if __has_builtin(__builtin_amdgcn_fdot2)
    union { u32 u; half2_t h; } a, b;
    a.u = w; b.u = hv;
    return __builtin_amdgcn_fdot2(a.h, b.h, acc, false);
#else
    union { u32 u; _Float16 h[2]; } a, b;
    a.u = w; b.u = hv;
    acc += (float)a.h[0] * (float)b.h[0];
    acc += (float)a.h[1] * (float)b.h[1];
    return acc;
#endif
}
__device__ __forceinline__ float sigm(float x) {
    return 1.0f / (1.0f + __expf(-x));
}
__device__ __forceinline__ float tanh_(float x) {
    float e = __expf(-2.0f * fabsf(x));
    float r = (1.0f - e) / (1.0f + e);
    return x < 0.0f ? -r : r;
}

// ---- zero the flag array (deterministic each launch; graph-safe) ----
__global__ __launch_bounds__(256) void zero_flags(u32* __restrict__ f)
{
    int i = blockIdx.x * 256 + threadIdx.x;   // 4096 u32 over 16 blocks
    f[i] = 0;
}

// ---- pack W_hh [1024][256] fp32 -> Wp[k2][j] = uint4{i,f,g,o} f16-pairs --
__global__ __launch_bounds__(256) void pack_whh(
    const float* __restrict__ W0, const float* __restrict__ W1,
    uint4* __restrict__ P0, uint4* __restrict__ P1)
{
    const int k2 = blockIdx.x;
    const int j  = threadIdx.x;
    const float* W = blockIdx.y ? W1 : W0;
    uint4*       P = blockIdx.y ? P1 : P0;
    uint4 v;
    u32* vp = &v.x;
#pragma unroll
    for (int g = 0; g < 4; ++g) {
        float2 w = *(const float2*)(W + (size_t)(g * 256 + j) * 256 + 2 * k2);
        vp[g] = (u32)f2h(w.x) | ((u32)f2h(w.y) << 16);
    }
    P[(size_t)k2 * 256 + j] = v;
}

// ---- pack W_ih [1024][256] fp32 -> f16 row-major (both layers) ----
__global__ __launch_bounds__(256) void pack_wih(
    const float* __restrict__ W0, const float* __restrict__ W1,
    u16* __restrict__ O0, u16* __restrict__ O1)
{
    const float* W = blockIdx.y ? W1 : W0;
    u16*         O = blockIdx.y ? O1 : O0;
    size_t i = (size_t)blockIdx.x * 256 + threadIdx.x;
    float4 v = ((const float4*)W)[i];
    u32 lo = (u32)f2h(v.x) | ((u32)f2h(v.y) << 16);
    u32 hi = (u32)f2h(v.z) | ((u32)f2h(v.w) << 16);
    uint2 u; u.x = lo; u.y = hi;
    ((uint2*)O)[i] = u;
}

// ---- xg GEMM (unchanged from v8): f16 MFMA, one WG per 64-row M-tile ----
template<int AHALF>
__global__ __launch_bounds__(256) void gemm_xg(
    const void* __restrict__ Av, const u16* __restrict__ Bh,
    u16* __restrict__ out, int tclog2, int Tstride, int t0)
{
    __shared__ __align__(16) u16 As[64][264];
    const int tid    = threadIdx.x;
    const int m0     = blockIdx.x * 64;
    const int tcmask = (1 << tclog2) - 1;

    if (AHALF) {
        const u16* Ah = (const u16*)Av;
#pragma unroll
        for (int it = 0; it < 8; ++it) {
            int idx = it * 256 + tid;
            int row = idx >> 5;
            int c8  = idx & 31;
            int m   = m0 + row;
            size_t grow = (size_t)(m >> tclog2) * Tstride + t0 + (m & tcmask);
            ushort8 v = *(const ushort8*)(Ah + grow * D_ + c8 * 8);
            *(ushort8*)(&As[row][c8 * 8]) = v;
        }
    } else {
        const float* Af = (const float*)Av;
#pragma unroll
        for (int it = 0; it < 16; ++it) {
            int idx = it * 256 + tid;
            int row = idx >> 6;
            int c4  = idx & 63;
            int m   = m0 + row;
            size_t grow = (size_t)(m >> tclog2) * Tstride + t0 + (m & tcmask);
            float4 v = *(const float4*)(Af + grow * D_ + c4 * 4);
            uint2 u;
            u.x = (u32)f2h(v.x) | ((u32)f2h(v.y) << 16);
            u.y = (u32)f2h(v.z) | ((u32)f2h(v.w) << 16);
            *(uint2*)(&As[row][c4 * 4]) = u;
        }
    }
    __syncthreads();

    const int l   = tid & 63;
    const int w   = tid >> 6;
    const int rl  = l & 15;
    const int kg  = l >> 4;
    const int rr0 = kg * 4;

    for (int nb = 0; nb < 8; ++nb) {
        const int n0 = nb * 128 + w * 32;
        f32x4 zz = {0.f, 0.f, 0.f, 0.f};
        f32x4 acc[4][2];
#pragma unroll
        for (int mi = 0; mi < 4; ++mi)
#pragma unroll
            for (int ni = 0; ni < 2; ++ni) acc[mi][ni] = zz;

#pragma unroll
        for (int ks = 0; ks < 8; ++ks) {
            const int k = ks * 32 + kg * 8;
            half8 a[4], bb[2];
#pragma unroll
            for (int mi = 0; mi < 4; ++mi)
                a[mi] = *(const half8*)(&As[mi * 16 + rl][k]);
#pragma unroll
            for (int ni = 0; ni < 2; ++ni)
                bb[ni] = *(const half8*)(Bh + (size_t)(n0 + ni * 16 + rl) * D_ + k);
#pragma unroll
            for (int mi = 0; mi < 4; ++mi)
#pragma unroll
                for (int ni = 0; ni < 2; ++ni)
                    acc[mi][ni] = __builtin_amdgcn_mfma_f32_16x16x32_f16(
                        a[mi], bb[ni], acc[mi][ni], 0, 0, 0);
        }

#pragma unroll
        for (int mi = 0; mi < 4; ++mi)
#pragma unroll
            for (int ni = 0; ni < 2; ++ni) {
                f32x4 d = acc[mi][ni];
                size_t mrow = (size_t)(m0 + mi * 16 + rr0);
                int col = n0 + ni * 16 + rl;
#pragma unroll
                for (int r = 0; r < 4; ++r)
                    out[(mrow + r) * G_ + col] = f2h(d[r]);
            }
    }
}

// ---- paired-WG scan: 256 WGs = 2 jobs x 64 b x 2 j-halves ----
// WG (jid, b, half) owns j_global in [half*128, half*128+128).
// 512 threads: tid = kq*128 + jl; kq 0..3 covers k2 [kq*32, kq*32+32)
//   -> h indices [kq*64, kq*64+64), i.e. h-half hh = kq>>1.
// Threads with hh==half read own h from LDS hf; others spin on partner's
// flag and read partner's published h-half from global hx (parity dbuf).
struct ScanJob {
    const _Float16* xg;      // [64][Tc][1024] f16
    const uint4*    Wp;      // [128][256]
    const float*    bias;    // [1024]
    float*          state;   // h[64][256], c[64][256]
    void*           h_out;   // f16 (houth=1) or fp32
    float*          hc_last; // may be null
    int Tc;                  // 0 = inactive
    int toff;                // h_out time offset
    int TS;                  // h_out time stride
    int houth;               // 1 = f16 h_out
    int first;               // 1 = zero-init state
    int tb;                  // absolute chunk time base (monotonic flags)
};

__global__ __launch_bounds__(512, 2) void lstm_scan2(
    ScanJob JA, ScanJob JB, u32* __restrict__ flags, uint4* __restrict__ hx)
{
    const int bx   = blockIdx.x;
    const int jid  = bx >> 7;            // 0 = job A, 1 = job B
    const ScanJob J = jid ? JB : JA;
    if (J.Tc == 0) return;
    const int b    = bx & 63;
    const int half = (bx >> 6) & 1;      // owned j-half
    const int tid  = threadIdx.x;
    const int jl   = tid & 127;          // local j
    const int kq   = tid >> 7;           // k-quarter 0..3
    const int jg   = half * 128 + jl;    // global j
    const int hh   = kq >> 1;            // h-half this thread's k-range needs

    // wl[10] rows allocated (9 used) to push LDS over 80KiB -> 1 WG/CU.
    __shared__ __align__(16) uint4  wl[NLD + 1][512];  // 81920 B
    __shared__ __align__(16) float4 red[3][128];       //  6144 B
    __shared__ __align__(16) u32    hf_p[128];         //   512 B (own half f16)

    // ---- weight residency: thread blocks k2 = kq*32 + p, row j = jg ----
    const uint4* wpb = J.Wp + (size_t)(kq * 32) * 256 + jg;
    uint4 wr[NRG];
#pragma unroll
    for (int p = 0; p < NRG; ++p)
        wr[p] = wpb[(size_t)p * 256];
#pragma unroll
    for (int p = 0; p < NLD; ++p)
        wl[p][tid] = wpb[(size_t)(NRG + p) * 256];

    // ---- flag / hx plumbing ----
    const int tb = J.tb;
    u32* flag_my = flags + (size_t)(((jid * 2 + half) * 64 + b)) * 16;
    u32* flag_pr = flags + (size_t)(((jid * 2 + (1 - half)) * 64 + b)) * 16;
    uint4* hx_my = hx + (size_t)(((jid * 64 + b) * 2 + half)) * 32;       // 2 parities x16
    const uint4* hx_pr = hx + (size_t)(((jid * 64 + b) * 2 + (1 - half))) * 32;
    const uint4* hfu = (const uint4*)hf_p;
    _Float16* hfh = (_Float16*)hf_p;
    const int sub = (kq & 1) * 8;        // uint4 offset within the h-half

    const int Tc = J.Tc;
    const int houth = J.houth;
    float h = 0.f, c = 0.f;
    float bi = 0.f, bf_ = 0.f, bg = 0.f, bo = 0.f;
    const _Float16* xg = J.xg;
    size_t xo = (size_t)b * Tc * G_ + jg;
    float nx0 = 0.f, nx1 = 0.f, nx2 = 0.f, nx3 = 0.f;

    if (kq == 0) {
        if (!J.first) {
            h = J.state[b * H_ + jg];
            c = J.state[B_ * H_ + b * H_ + jg];
        }
        bi  = J.bias[jg];
        bf_ = J.bias[256 + jg];
        bg  = J.bias[512 + jg];
        bo  = J.bias[768 + jg];
        hfh[jl] = (_Float16)h;
        // initial publish of h(tb-1) into parity (tb-1)&1
        ((u16*)(hx_my + (size_t)((tb - 1) & 1) * 16))[jl] = f2h(h);
        nx0 = (float)xg[xo];       nx1 = (float)xg[xo + 256];
        nx2 = (float)xg[xo + 512]; nx3 = (float)xg[xo + 768];
    }
    float* hof = (float*)J.h_out;
    u16*   hoh = (u16*)J.h_out;
    size_t ho = ((size_t)b * J.TS + J.toff) * H_ + jg;
    __syncthreads();
    if (tid == 128) {
        __threadfence();
        __hip_atomic_store(flag_my, (u32)tb, __ATOMIC_RELEASE,
                           __HIP_MEMORY_SCOPE_AGENT);
    }

    for (int t = 0; t < Tc; ++t) {
        float a0, a1, a2, a3;
        if (kq == 0) {
            a0 = nx0 + bi; a1 = nx1 + bf_; a2 = nx2 + bg; a3 = nx3 + bo;
            if (t + 1 < Tc) xo += G_;            // clamped prefetch
            nx0 = (float)xg[xo];       nx1 = (float)xg[xo + 256];
            nx2 = (float)xg[xo + 512]; nx3 = (float)xg[xo + 768];
        } else {
            a0 = a1 = a2 = a3 = 0.f;
        }

        // ---- acquire h(tb+t-1) slice for this thread's k-range ----
        uint4 hvv[8];
        if (hh == half) {
#pragma unroll
            for (int i = 0; i < 8; ++i) hvv[i] = hfu[sub + i];
        } else {
            const u32 want = (u32)(tb + t);
            while (__hip_atomic_load(flag_pr, __ATOMIC_ACQUIRE,
                                     __HIP_MEMORY_SCOPE_AGENT) < want) {}
            const uint4* src = hx_pr + (size_t)((tb + t - 1) & 1) * 16 + sub;
#pragma unroll
            for (int i = 0; i < 8; ++i) hvv[i] = src[i];
        }

        // ---- dot over 32 k2-blocks ----
#pragma unroll
        for (int i = 0; i < 8; ++i) {
            const u32* hq = (const u32*)&hvv[i];
#pragma unroll
            for (int q = 0; q < 4; ++q) {
                const int p = 4 * i + q;         // compile-time
                uint4 wv;
                if (p < NRG) wv = wr[p];
                else         wv = wl[p - NRG][tid];
                u32 hv = hq[q];
                a0 = dot2(wv.x, hv, a0);
                a1 = dot2(wv.y, hv, a1);
                a2 = dot2(wv.z, hv, a2);
                a3 = dot2(wv.w, hv, a3);
            }
        }

        if (kq > 0) {
            float4 r4; r4.x = a0; r4.y = a1; r4.z = a2; r4.w = a3;
            red[kq - 1][jl] = r4;
        }
        __syncthreads();   // partials visible; all hf reads of step done
        if (kq == 0) {
            float4 p0 = red[0][jl];
            float4 p1 = red[1][jl];
            float4 p2 = red[2][jl];
            a0 += p0.x + p1.x + p2.x;
            a1 += p0.y + p1.y + p2.y;
            a2 += p0.z + p1.z + p2.z;
            a3 += p0.w + p1.w + p2.w;
            float i_ = sigm(a0);
            float f_ = sigm(a1);
            float g_ = tanh_(a2);
            float o_ = sigm(a3);
            c = f_ * c + i_ * g_;
            float hn = o_ * tanh_(c);
            h = hn;
            hfh[jl] = (_Float16)hn;
            ((u16*)(hx_my + (size_t)((tb + t) & 1) * 16))[jl] = f2h(hn);
            if (houth) hoh[ho] = f2h(hn);
            else       __builtin_nontemporal_store(hn, hof + ho);
            ho += H_;
        }
        __syncthreads();   // new hf/hx written; publish then next step
        if (tid == 128) {
            __threadfence();
            __hip_atomic_store(flag_my, (u32)(tb + t + 1), __ATOMIC_RELEASE,
                               __HIP_MEMORY_SCOPE_AGENT);
        }
    }

    if (kq == 0) {
        J.state[b * H_ + jg] = h;
        J.state[B_ * H_ + b * H_ + jg] = c;
        if (J.hc_last) {
            J.hc_last[b * H_ + jg] = h;
            J.hc_last[B_ * H_ + b * H_ + jg] = c;
        }
    }
}

extern "C" void kernel_launch(void* const* d_in, const int* in_sizes, int n_in,
                              void* d_out, int out_size, void* d_ws, size_t ws_size,
                              hipStream_t stream)
{
    (void)in_sizes; (void)n_in; (void)out_size;

    const float* x    = (const float*)d_in[0];
    const float* Wih0 = (const float*)d_in[1];
    const float* Whh0 = (const float*)d_in[2];
    const float* b0   = (const float*)d_in[3];
    const float* Wih1 = (const float*)d_in[4];
    const float* Whh1 = (const float*)d_in[5];
    const float* b1   = (const float*)d_in[6];

    float* out   = (float*)d_out;
    float* hlast = out + (size_t)B_ * T_ * H_;

    // ws layout
    char* ws = (char*)d_ws;
    const size_t WPB  = (size_t)128 * 256 * 16;     // 524288 per packed W_hh
    const size_t WIHB = (size_t)1024 * 256 * 2;     // 524288 per f16 W_ih
    const size_t STB  = (size_t)2 * B_ * H_ * 4;    // 131072 per-layer state
    const size_t FLB  = (size_t)4096 * 4;           //  16384 flags
    const size_t HXB  = (size_t)2 * 64 * 2 * 2 * 256; // 131072 hx
    uint4* Wp0    = (uint4*)(ws);
    uint4* Wp1    = (uint4*)(ws + WPB);
    u16*   Wih0h  = (u16*)(ws + 2 * WPB);
    u16*   Wih1h  = (u16*)(ws + 2 * WPB + WIHB);
    float* state0 = (float*)(ws + 2 * WPB + 2 * WIHB);
    float* state1 = (float*)(ws + 2 * WPB + 2 * WIHB + STB);
    u32*   flags  = (u32*)(ws + 2 * WPB + 2 * WIHB + 2 * STB);
    uint4* hx     = (uint4*)(ws + 2 * WPB + 2 * WIHB + 2 * STB + FLB);
    const size_t BASE = 2 * WPB + 2 * WIHB + 2 * STB + FLB + HXB; // 2506752

    // Tc: largest power-of-2 <= 256 fitting ws.
    // per-Tc bytes: h1c 32768 + xgA/xgB 2*131072 = 294912
    int Tc = 16;
    for (int tc = 256; tc >= 16; tc >>= 1)
        if (BASE + (size_t)tc * 294912 <= ws_size) { Tc = tc; break; }
    const int nch    = T_ / Tc;
    const int tclog2 = 31 - __builtin_clz((unsigned)Tc);
    const size_t H1CB = (size_t)B_ * Tc * H_ * 2;
    const size_t XGB  = (size_t)B_ * Tc * G_ * 2;
    u16*      h1c = (u16*)(ws + BASE);
    _Float16* xgA = (_Float16*)(ws + BASE + H1CB);
    _Float16* xgB = (_Float16*)(ws + BASE + H1CB + XGB);

    zero_flags<<<16, 256, 0, stream>>>(flags);
    pack_whh<<<dim3(128, 2), 256, 0, stream>>>(Whh0, Whh1, Wp0, Wp1);
    pack_wih<<<dim3(256, 2), 256, 0, stream>>>(Wih0, Wih1, Wih0h, Wih1h);

    const int gemmWG = (B_ * Tc) / 64;

    // prologue: xg for layer-0 chunk 0
    gemm_xg<0><<<gemmWG, 256, 0, stream>>>(x, Wih0h, (u16*)xgA, tclog2, T_, 0);

    for (int s = 0; s <= nch; ++s) {
        ScanJob JA = {}; JA.Tc = 0;
        ScanJob JB = {}; JB.Tc = 0;
        if (s < nch) {                      // layer 0, chunk s
            JA.xg = xgA;  JA.Wp = Wp0;  JA.bias = b0;  JA.state = state0;
            JA.h_out = h1c;  JA.hc_last = nullptr;
            JA.Tc = Tc;  JA.toff = 0;  JA.TS = Tc;  JA.houth = 1;
            JA.first = (s == 0);  JA.tb = s * Tc;
        }
        if (s >= 1) {                       // layer 1, chunk s-1
            int cc = s - 1;
            JB.xg = xgB;  JB.Wp = Wp1;  JB.bias = b1;  JB.state = state1;
            JB.h_out = out;  JB.hc_last = (cc == nch - 1) ? hlast : nullptr;
            JB.Tc = Tc;  JB.toff = cc * Tc;  JB.TS = T_;  JB.houth = 0;
            JB.first = (cc == 0);  JB.tb = cc * Tc;
        }
        lstm_scan2<<<256, 512, 0, stream>>>(JA, JB, flags, hx);

        if (s + 1 < nch)                    // xg for layer-0 chunk s+1
            gemm_xg<0><<<gemmWG, 256, 0, stream>>>(
                x, Wih0h, (u16*)xgA, tclog2, T_, (s + 1) * Tc);
        if (s < nch)                        // xg for layer-1 chunk s (from h1c)
            gemm_xg<1><<<gemmWG, 256, 0, stream>>>(
                h1c, Wih1h, (u16*)xgB, tclog2, Tc, 0);
    }
}

// Round 11
// 8317.528 us; speedup vs baseline: 5.2394x; 5.2394x over previous
//
#include <hip/hip_runtime.h>
#include <hip/hip_bf16.h>

// 2-layer LSTM, B=64 T=2048 D=H=256, fp32 I/O.
// v11 = v8 pipeline + reworked scan.
//   v10 lesson: per-step cross-WG sync = 20us/step. DEAD. Chunk-level
//   dispatch-order pipelining (v8) retained.
//   v8 scan analysis: LDS-issue-bound (34 b128-class reads/thread/step) +
//   2 barriers. v11: (1) weights 36 VGPR + 12 LDS + 16 STREAMED from L2 per
//   step (step-invariant, L2-hot; rides VMEM pipe, hidden >=300cyc);
//   (2) wave = 32j x 2kh lanes -> k-reduce via v_permlane32_swap_b32 (VALU),
//   no red[] LDS, barrier #1 eliminated; (3) h parity double-buffer in LDS
//   -> ONE barrier/step.

typedef unsigned short u16;
typedef unsigned int   u32;

typedef __attribute__((ext_vector_type(8))) _Float16       half8;
typedef __attribute__((ext_vector_type(2))) _Float16       half2_t;
typedef __attribute__((ext_vector_type(8))) unsigned short ushort8;
typedef __attribute__((ext_vector_type(4))) float          f32x4;

#define B_  64
#define T_  2048
#define D_  256
#define H_  256
#define G_  1024   // 4*H

#define NRG  36    // scan: k2-blocks per thread in VGPRs
#define NLDW 12    // scan: k2-blocks per thread in LDS
#define NST  16    // scan: k2-blocks streamed from L2 per step (2 batches x8)
static_assert(NRG + NLDW + NST == 64, "k-half coverage");

// ---- helpers ----
__device__ __forceinline__ u16 f2h(float f) {
    union { _Float16 h; u16 b; } v; v.h = (_Float16)f; return v.b;
}
__device__ __forceinline__ float dot2(u32 w, u32 hv, float acc) {
#if __has_builtin(__builtin_amdgcn_fdot2)
    union { u32 u; half2_t h; } a, b;
    a.u = w; b.u = hv;
    return __builtin_amdgcn_fdot2(a.h, b.h, acc, false);
#else
    union { u32 u; _Float16 h[2]; } a, b;
    a.u = w; b.u = hv;
    acc += (float)a.h[0] * (float)b.h[0];
    acc += (float)a.h[1] * (float)b.h[1];
    return acc;
#endif
}
// sum of lane l and lane l^32 (wave64), pure VALU via v_permlane32_swap_b32
__device__ __forceinline__ float pl32_red(float x) {
    u32 u = __float_as_uint(x), v = u;
    asm("v_permlane32_swap_b32 %0, %1" : "+v"(u), "+v"(v));
    return __uint_as_float(u) + __uint_as_float(v);
}
__device__ __forceinline__ float sigm(float x) {
    return 1.0f / (1.0f + __expf(-x));
}
__device__ __forceinline__ float tanh_(float x) {
    float e = __expf(-2.0f * fabsf(x));
    float r = (1.0f - e) / (1.0f + e);
    return x < 0.0f ? -r : r;
}

// ---- pack W_hh [1024][256] fp32 -> Wp[k2][j] = uint4{i,f,g,o} f16-pairs --
__global__ __launch_bounds__(256) void pack_whh(
    const float* __restrict__ W0, const float* __restrict__ W1,
    uint4* __restrict__ P0, uint4* __restrict__ P1)
{
    const int k2 = blockIdx.x;
    const int j  = threadIdx.x;
    const float* W = blockIdx.y ? W1 : W0;
    uint4*       P = blockIdx.y ? P1 : P0;
    uint4 v;
    u32* vp = &v.x;
#pragma unroll
    for (int g = 0; g < 4; ++g) {
        float2 w = *(const float2*)(W + (size_t)(g * 256 + j) * 256 + 2 * k2);
        vp[g] = (u32)f2h(w.x) | ((u32)f2h(w.y) << 16);
    }
    P[(size_t)k2 * 256 + j] = v;
}

// ---- pack W_ih [1024][256] fp32 -> f16 row-major (both layers) ----
__global__ __launch_bounds__(256) void pack_wih(
    const float* __restrict__ W0, const float* __restrict__ W1,
    u16* __restrict__ O0, u16* __restrict__ O1)
{
    const float* W = blockIdx.y ? W1 : W0;
    u16*         O = blockIdx.y ? O1 : O0;
    size_t i = (size_t)blockIdx.x * 256 + threadIdx.x;
    float4 v = ((const float4*)W)[i];
    u32 lo = (u32)f2h(v.x) | ((u32)f2h(v.y) << 16);
    u32 hi = (u32)f2h(v.z) | ((u32)f2h(v.w) << 16);
    uint2 u; u.x = lo; u.y = hi;
    ((uint2*)O)[i] = u;
}

// ---- xg GEMM (v8, unchanged): f16 MFMA, one WG per 64-row M-tile ----
template<int AHALF>
__global__ __launch_bounds__(256) void gemm_xg(
    const void* __restrict__ Av, const u16* __restrict__ Bh,
    u16* __restrict__ out, int tclog2, int Tstride, int t0)
{
    __shared__ __align__(16) u16 As[64][264];
    const int tid    = threadIdx.x;
    const int m0     = blockIdx.x * 64;
    const int tcmask = (1 << tclog2) - 1;

    if (AHALF) {
        const u16* Ah = (const u16*)Av;
#pragma unroll
        for (int it = 0; it < 8; ++it) {
            int idx = it * 256 + tid;
            int row = idx >> 5;
            int c8  = idx & 31;
            int m   = m0 + row;
            size_t grow = (size_t)(m >> tclog2) * Tstride + t0 + (m & tcmask);
            ushort8 v = *(const ushort8*)(Ah + grow * D_ + c8 * 8);
            *(ushort8*)(&As[row][c8 * 8]) = v;
        }
    } else {
        const float* Af = (const float*)Av;
#pragma unroll
        for (int it = 0; it < 16; ++it) {
            int idx = it * 256 + tid;
            int row = idx >> 6;
            int c4  = idx & 63;
            int m   = m0 + row;
            size_t grow = (size_t)(m >> tclog2) * Tstride + t0 + (m & tcmask);
            float4 v = *(const float4*)(Af + grow * D_ + c4 * 4);
            uint2 u;
            u.x = (u32)f2h(v.x) | ((u32)f2h(v.y) << 16);
            u.y = (u32)f2h(v.z) | ((u32)f2h(v.w) << 16);
            *(uint2*)(&As[row][c4 * 4]) = u;
        }
    }
    __syncthreads();

    const int l   = tid & 63;
    const int w   = tid >> 6;
    const int rl  = l & 15;
    const int kg  = l >> 4;
    const int rr0 = kg * 4;

    for (int nb = 0; nb < 8; ++nb) {
        const int n0 = nb * 128 + w * 32;
        f32x4 zz = {0.f, 0.f, 0.f, 0.f};
        f32x4 acc[4][2];
#pragma unroll
        for (int mi = 0; mi < 4; ++mi)
#pragma unroll
            for (int ni = 0; ni < 2; ++ni) acc[mi][ni] = zz;

#pragma unroll
        for (int ks = 0; ks < 8; ++ks) {
            const int k = ks * 32 + kg * 8;
            half8 a[4], bb[2];
#pragma unroll
            for (int mi = 0; mi < 4; ++mi)
                a[mi] = *(const half8*)(&As[mi * 16 + rl][k]);
#pragma unroll
            for (int ni = 0; ni < 2; ++ni)
                bb[ni] = *(const half8*)(Bh + (size_t)(n0 + ni * 16 + rl) * D_ + k);
#pragma unroll
            for (int mi = 0; mi < 4; ++mi)
#pragma unroll
                for (int ni = 0; ni < 2; ++ni)
                    acc[mi][ni] = __builtin_amdgcn_mfma_f32_16x16x32_f16(
                        a[mi], bb[ni], acc[mi][ni], 0, 0, 0);
        }

#pragma unroll
        for (int mi = 0; mi < 4; ++mi)
#pragma unroll
            for (int ni = 0; ni < 2; ++ni) {
                f32x4 d = acc[mi][ni];
                size_t mrow = (size_t)(m0 + mi * 16 + rr0);
                int col = n0 + ni * 16 + rl;
#pragma unroll
                for (int r = 0; r < 4; ++r)
                    out[(mrow + r) * G_ + col] = f2h(d[r]);
            }
    }
}

// ---- dual-job scan v11: 128 WGs = 2 jobs x 64 batch ----
// 512 thr; wave w: lanes = 32 j (w*32..w*32+31) x 2 kh halves.
// Thread (j,kh) k2-range [kh*64, kh*64+64): 36 VGPR + 12 LDS + 16 L2-stream.
// k-reduce = permlane32_swap; h parity double-buffer; ONE barrier/step.
struct ScanJob {
    const _Float16* xg;      // [64][Tc][1024] f16
    const uint4*    Wp;      // [128][256]
    const float*    bias;    // [1024]
    float*          state;   // h[64][256], c[64][256]
    void*           h_out;   // f16 (houth=1) or fp32
    float*          hc_last; // may be null
    int Tc;                  // 0 = inactive
    int toff;                // h_out time offset
    int TS;                  // h_out time stride
    int houth;               // 1 = f16 h_out
    int first;               // 1 = zero-init state
};

__global__ __launch_bounds__(512, 2) void lstm_scan2(ScanJob JA, ScanJob JB)
{
    const ScanJob J = (blockIdx.x >= 64) ? JB : JA;
    if (J.Tc == 0) return;
    const int b    = blockIdx.x & 63;
    const int tid  = threadIdx.x;
    const int w    = tid >> 6;
    const int lane = tid & 63;
    const int kh   = lane >> 5;          // k-half
    const int jl   = lane & 31;
    const int j    = w * 32 + jl;        // hidden unit (0..255)

    __shared__ __align__(16) uint4    wl[NLDW][512];   // 98304 B
    __shared__ __align__(16) _Float16 hf2[2][256];     //  1024 B

    // ---- weight residency: k2 = kh*64 + p ----
    const uint4* wpb = J.Wp + (size_t)(kh * 64) * 256 + j;
    uint4 wr[NRG];
#pragma unroll
    for (int p = 0; p < NRG; ++p)
        wr[p] = wpb[(size_t)p * 256];
#pragma unroll
    for (int p = 0; p < NLDW; ++p)
        wl[p][tid] = wpb[(size_t)(NRG + p) * 256];
    const uint4* wst = wpb + (size_t)(NRG + NLDW) * 256;   // 16 streamed blocks

    const int Tc    = J.Tc;
    const int houth = J.houth;
    float h = 0.f, c = 0.f;
    float bi = 0.f, bf_ = 0.f, bg = 0.f, bo = 0.f;
    const _Float16* xg = J.xg;
    size_t xo = (size_t)b * Tc * G_ + j;
    float nx0 = 0.f, nx1 = 0.f, nx2 = 0.f, nx3 = 0.f;

    if (!J.first)                        // c in ALL lanes (redundant epilogue)
        c = J.state[B_ * H_ + b * H_ + j];
    if (kh == 0) {
        if (!J.first) h = J.state[b * H_ + j];
        bi  = J.bias[j];
        bf_ = J.bias[256 + j];
        bg  = J.bias[512 + j];
        bo  = J.bias[768 + j];
        hf2[0][j] = (_Float16)h;         // step 0 reads parity 0
        nx0 = (float)xg[xo];       nx1 = (float)xg[xo + 256];
        nx2 = (float)xg[xo + 512]; nx3 = (float)xg[xo + 768];
    }
    float* hof = (float*)J.h_out;
    u16*   hoh = (u16*)J.h_out;
    size_t ho = ((size_t)b * J.TS + J.toff) * H_ + j;
    __syncthreads();

    for (int t = 0; t < Tc; ++t) {
        const int par = t & 1;
        // stream batch 1 (blocks 48..55) — consumed at i=12,13
        uint4 s1[8];
#pragma unroll
        for (int s = 0; s < 8; ++s) s1[s] = wst[(size_t)s * 256];

        float a0, a1, a2, a3;
        if (kh == 0) {
            a0 = nx0 + bi; a1 = nx1 + bf_; a2 = nx2 + bg; a3 = nx3 + bo;
            if (t + 1 < Tc) xo += G_;            // clamped prefetch
            nx0 = (float)xg[xo];       nx1 = (float)xg[xo + 256];
            nx2 = (float)xg[xo + 512]; nx3 = (float)xg[xo + 768];
        } else {
            a0 = a1 = a2 = a3 = 0.f;
        }

        const uint4* hvp = ((const uint4*)hf2[par]) + kh * 16;
        uint4 s2[8];
#pragma unroll
        for (int i = 0; i < 16; ++i) {
            if (i == 9) {                // stream batch 2 (blocks 56..63)
#pragma unroll
                for (int s = 0; s < 8; ++s) s2[s] = wst[(size_t)(8 + s) * 256];
            }
            uint4 hv4 = hvp[i];
            const u32* hq = &hv4.x;
#pragma unroll
            for (int q = 0; q < 4; ++q) {
                const int p = 4 * i + q;         // compile-time
                uint4 wv;
                if (p < NRG)                wv = wr[p];
                else if (p < NRG + NLDW)    wv = wl[p - NRG][tid];
                else if (p < NRG + NLDW + 8) wv = s1[p - NRG - NLDW];
                else                         wv = s2[p - NRG - NLDW - 8];
                u32 hv = hq[q];
                a0 = dot2(wv.x, hv, a0);
                a1 = dot2(wv.y, hv, a1);
                a2 = dot2(wv.z, hv, a2);
                a3 = dot2(wv.w, hv, a3);
            }
        }

        // cross-half reduce: lane l + lane l^32 (same j, other kh)
        a0 = pl32_red(a0);
        a1 = pl32_red(a1);
        a2 = pl32_red(a2);
        a3 = pl32_red(a3);

        // epilogue in ALL lanes (c replicated deterministically)
        float i_ = sigm(a0);
        float f_ = sigm(a1);
        float g_ = tanh_(a2);
        float o_ = sigm(a3);
        c = f_ * c + i_ * g_;
        float hn = o_ * tanh_(c);
        h = hn;
        if (kh == 0) {
            hf2[par ^ 1][j] = (_Float16)hn;      // next step's buffer
            if (houth) hoh[ho] = f2h(hn);
            else       __builtin_nontemporal_store(hn, hof + ho);
            ho += H_;
        }
        __syncthreads();                 // hf2[par^1] visible to all waves
    }

    if (kh == 0) {
        J.state[b * H_ + j] = h;
        J.state[B_ * H_ + b * H_ + j] = c;
        if (J.hc_last) {
            J.hc_last[b * H_ + j] = h;
            J.hc_last[B_ * H_ + b * H_ + j] = c;
        }
    }
}

extern "C" void kernel_launch(void* const* d_in, const int* in_sizes, int n_in,
                              void* d_out, int out_size, void* d_ws, size_t ws_size,
                              hipStream_t stream)
{
    (void)in_sizes; (void)n_in; (void)out_size;

    const float* x    = (const float*)d_in[0];
    const float* Wih0 = (const float*)d_in[1];
    const float* Whh0 = (const float*)d_in[2];
    const float* b0   = (const float*)d_in[3];
    const float* Wih1 = (const float*)d_in[4];
    const float* Whh1 = (const float*)d_in[5];
    const float* b1   = (const float*)d_in[6];

    float* out   = (float*)d_out;
    float* hlast = out + (size_t)B_ * T_ * H_;

    // ws layout (v8)
    char* ws = (char*)d_ws;
    const size_t WPB  = (size_t)128 * 256 * 16;     // 524288 per packed W_hh
    const size_t WIHB = (size_t)1024 * 256 * 2;     // 524288 per f16 W_ih
    const size_t STB  = (size_t)2 * B_ * H_ * 4;    // 131072 per-layer state
    uint4* Wp0    = (uint4*)(ws);
    uint4* Wp1    = (uint4*)(ws + WPB);
    u16*   Wih0h  = (u16*)(ws + 2 * WPB);
    u16*   Wih1h  = (u16*)(ws + 2 * WPB + WIHB);
    float* state0 = (float*)(ws + 2 * WPB + 2 * WIHB);
    float* state1 = (float*)(ws + 2 * WPB + 2 * WIHB + STB);
    const size_t BASE = 2 * WPB + 2 * WIHB + 2 * STB;   // 2359296

    // Tc: largest power-of-2 <= 256 fitting ws.
    int Tc = 16;
    for (int tc = 256; tc >= 16; tc >>= 1)
        if (BASE + (size_t)tc * 294912 <= ws_size) { Tc = tc; break; }
    const int nch    = T_ / Tc;
    const int tclog2 = 31 - __builtin_clz((unsigned)Tc);
    const size_t H1CB = (size_t)B_ * Tc * H_ * 2;
    const size_t XGB  = (size_t)B_ * Tc * G_ * 2;
    u16*      h1c = (u16*)(ws + BASE);
    _Float16* xgA = (_Float16*)(ws + BASE + H1CB);
    _Float16* xgB = (_Float16*)(ws + BASE + H1CB + XGB);

    pack_whh<<<dim3(128, 2), 256, 0, stream>>>(Whh0, Whh1, Wp0, Wp1);
    pack_wih<<<dim3(256, 2), 256, 0, stream>>>(Wih0, Wih1, Wih0h, Wih1h);

    const int gemmWG = (B_ * Tc) / 64;

    // prologue: xg for layer-0 chunk 0
    gemm_xg<0><<<gemmWG, 256, 0, stream>>>(x, Wih0h, (u16*)xgA, tclog2, T_, 0);

    for (int s = 0; s <= nch; ++s) {
        ScanJob JA = {}; JA.Tc = 0;
        ScanJob JB = {}; JB.Tc = 0;
        if (s < nch) {                      // layer 0, chunk s
            JA.xg = xgA;  JA.Wp = Wp0;  JA.bias = b0;  JA.state = state0;
            JA.h_out = h1c;  JA.hc_last = nullptr;
            JA.Tc = Tc;  JA.toff = 0;  JA.TS = Tc;  JA.houth = 1;
            JA.first = (s == 0);
        }
        if (s >= 1) {                       // layer 1, chunk s-1
            int cc = s - 1;
            JB.xg = xgB;  JB.Wp = Wp1;  JB.bias = b1;  JB.state = state1;
            JB.h_out = out;  JB.hc_last = (cc == nch - 1) ? hlast : nullptr;
            JB.Tc = Tc;  JB.toff = cc * Tc;  JB.TS = T_;  JB.houth = 0;
            JB.first = (cc == 0);
        }
        lstm_scan2<<<128, 512, 0, stream>>>(JA, JB);

        if (s + 1 < nch)                    // xg for layer-0 chunk s+1
            gemm_xg<0><<<gemmWG, 256, 0, stream>>>(
                x, Wih0h, (u16*)xgA, tclog2, T_, (s + 1) * Tc);
        if (s < nch)                        // xg for layer-1 chunk s (from h1c)
            gemm_xg<1><<<gemmWG, 256, 0, stream>>>(
                h1c, Wih1h, (u16*)xgB, tclog2, Tc, 0);
    }
}

// Round 12
// 4754.012 us; speedup vs baseline: 9.1667x; 1.7496x over previous
//
#include <hip/hip_runtime.h>
#include <hip/hip_bf16.h>

// 2-layer LSTM, B=64 T=2048 D=H=256, fp32 I/O.
// v12 = v8 resident-weight scan + v11's cheap mechanics (no streaming).
//   Lessons: v10 per-step cross-WG sync = dead. v11 per-step L2 weight
//   streaming = dead (weights must be CU-resident: regs+LDS only).
//   v12 changes vs v8 (each individually validated):
//   (1) wave = 32j x 2kh -> k-reduce via v_permlane32_swap_b32 (no red[] LDS);
//   (2) h parity double-buffer -> ONE barrier/step;
//   (3) all-lane epilogue (c replicated, deterministic);
//   (4) fused dual-gemm dispatch per slot (saves launch overhead).
//   Weights: NRG=46 VGPR + NLD=18 LDS per thread (v8 exact split).

typedef unsigned short u16;
typedef unsigned int   u32;

typedef __attribute__((ext_vector_type(8))) _Float16       half8;
typedef __attribute__((ext_vector_type(2))) _Float16       half2_t;
typedef __attribute__((ext_vector_type(8))) unsigned short ushort8;
typedef __attribute__((ext_vector_type(4))) float          f32x4;

#define B_  64
#define T_  2048
#define D_  256
#define H_  256
#define G_  1024   // 4*H

#define NRG 46     // scan: k2-blocks per thread in VGPRs
#define NLD 18     // scan: k2-blocks per thread in LDS (NRG+NLD = 64)
static_assert(NRG + NLD == 64, "k-half coverage");

// ---- helpers ----
__device__ __forceinline__ u16 f2h(float f) {
    union { _Float16 h; u16 b; } v; v.h = (_Float16)f; return v.b;
}
__device__ __forceinline__ float dot2(u32 w, u32 hv, float acc) {
#if __has_builtin(__builtin_amdgcn_fdot2)
    union { u32 u; half2_t h; } a, b;
    a.u = w; b.u = hv;
    return __builtin_amdgcn_fdot2(a.h, b.h, acc, false);
#else
    union { u32 u; _Float16 h[2]; } a, b;
    a.u = w; b.u = hv;
    acc += (float)a.h[0] * (float)b.h[0];
    acc += (float)a.h[1] * (float)b.h[1];
    return acc;
#endif
}
// sum of lane l and lane l^32 (wave64), pure VALU (validated in v11)
__device__ __forceinline__ float pl32_red(float x) {
    u32 u = __float_as_uint(x), v = u;
    asm("v_permlane32_swap_b32 %0, %1" : "+v"(u), "+v"(v));
    return __uint_as_float(u) + __uint_as_float(v);
}
__device__ __forceinline__ float sigm(float x) {
    return 1.0f / (1.0f + __expf(-x));
}
__device__ __forceinline__ float tanh_(float x) {
    float e = __expf(-2.0f * fabsf(x));
    float r = (1.0f - e) / (1.0f + e);
    return x < 0.0f ? -r : r;
}

// ---- pack W_hh [1024][256] fp32 -> Wp[k2][j] = uint4{i,f,g,o} f16-pairs --
__global__ __launch_bounds__(256) void pack_whh(
    const float* __restrict__ W0, const float* __restrict__ W1,
    uint4* __restrict__ P0, uint4* __restrict__ P1)
{
    const int k2 = blockIdx.x;
    const int j  = threadIdx.x;
    const float* W = blockIdx.y ? W1 : W0;
    uint4*       P = blockIdx.y ? P1 : P0;
    uint4 v;
    u32* vp = &v.x;
#pragma unroll
    for (int g = 0; g < 4; ++g) {
        float2 w = *(const float2*)(W + (size_t)(g * 256 + j) * 256 + 2 * k2);
        vp[g] = (u32)f2h(w.x) | ((u32)f2h(w.y) << 16);
    }
    P[(size_t)k2 * 256 + j] = v;
}

// ---- pack W_ih [1024][256] fp32 -> f16 row-major (both layers) ----
__global__ __launch_bounds__(256) void pack_wih(
    const float* __restrict__ W0, const float* __restrict__ W1,
    u16* __restrict__ O0, u16* __restrict__ O1)
{
    const float* W = blockIdx.y ? W1 : W0;
    u16*         O = blockIdx.y ? O1 : O0;
    size_t i = (size_t)blockIdx.x * 256 + threadIdx.x;
    float4 v = ((const float4*)W)[i];
    u32 lo = (u32)f2h(v.x) | ((u32)f2h(v.y) << 16);
    u32 hi = (u32)f2h(v.z) | ((u32)f2h(v.w) << 16);
    uint2 u; u.x = lo; u.y = hi;
    ((uint2*)O)[i] = u;
}

// ---- fused dual xg GEMM: blockIdx.y selects job; f16 MFMA ----
// Per job: one WG per 64-row M-tile, A staged once in LDS f16, full N loop.
struct GemmJob {
    const void* Av;      // fp32 (ahalf=0) or f16 (ahalf=1)
    const u16*  Bh;      // [1024][256] f16
    u16*        out;     // [B*Tc][1024] f16
    int tclog2, Tstride, t0, ahalf, active;
};

__global__ __launch_bounds__(256) void gemm_xg2(GemmJob GA, GemmJob GB)
{
    const GemmJob G = blockIdx.y ? GB : GA;
    if (!G.active) return;
    __shared__ __align__(16) u16 As[64][264];
    const int tid    = threadIdx.x;
    const int m0     = blockIdx.x * 64;
    const int tcmask = (1 << G.tclog2) - 1;

    if (G.ahalf) {
        const u16* Ah = (const u16*)G.Av;
#pragma unroll
        for (int it = 0; it < 8; ++it) {
            int idx = it * 256 + tid;
            int row = idx >> 5;
            int c8  = idx & 31;
            int m   = m0 + row;
            size_t grow = (size_t)(m >> G.tclog2) * G.Tstride + G.t0 + (m & tcmask);
            ushort8 v = *(const ushort8*)(Ah + grow * D_ + c8 * 8);
            *(ushort8*)(&As[row][c8 * 8]) = v;
        }
    } else {
        const float* Af = (const float*)G.Av;
#pragma unroll
        for (int it = 0; it < 16; ++it) {
            int idx = it * 256 + tid;
            int row = idx >> 6;
            int c4  = idx & 63;
            int m   = m0 + row;
            size_t grow = (size_t)(m >> G.tclog2) * G.Tstride + G.t0 + (m & tcmask);
            float4 v = *(const float4*)(Af + grow * D_ + c4 * 4);
            uint2 u;
            u.x = (u32)f2h(v.x) | ((u32)f2h(v.y) << 16);
            u.y = (u32)f2h(v.z) | ((u32)f2h(v.w) << 16);
            *(uint2*)(&As[row][c4 * 4]) = u;
        }
    }
    __syncthreads();

    const int l   = tid & 63;
    const int w   = tid >> 6;
    const int rl  = l & 15;
    const int kg  = l >> 4;
    const int rr0 = kg * 4;
    u16* out = G.out;

    for (int nb = 0; nb < 8; ++nb) {
        const int n0 = nb * 128 + w * 32;
        f32x4 zz = {0.f, 0.f, 0.f, 0.f};
        f32x4 acc[4][2];
#pragma unroll
        for (int mi = 0; mi < 4; ++mi)
#pragma unroll
            for (int ni = 0; ni < 2; ++ni) acc[mi][ni] = zz;

#pragma unroll
        for (int ks = 0; ks < 8; ++ks) {
            const int k = ks * 32 + kg * 8;
            half8 a[4], bb[2];
#pragma unroll
            for (int mi = 0; mi < 4; ++mi)
                a[mi] = *(const half8*)(&As[mi * 16 + rl][k]);
#pragma unroll
            for (int ni = 0; ni < 2; ++ni)
                bb[ni] = *(const half8*)(G.Bh + (size_t)(n0 + ni * 16 + rl) * D_ + k);
#pragma unroll
            for (int mi = 0; mi < 4; ++mi)
#pragma unroll
                for (int ni = 0; ni < 2; ++ni)
                    acc[mi][ni] = __builtin_amdgcn_mfma_f32_16x16x32_f16(
                        a[mi], bb[ni], acc[mi][ni], 0, 0, 0);
        }

        // C/D layout: col = lane&15, row = (lane>>4)*4 + reg
#pragma unroll
        for (int mi = 0; mi < 4; ++mi)
#pragma unroll
            for (int ni = 0; ni < 2; ++ni) {
                f32x4 d = acc[mi][ni];
                size_t mrow = (size_t)(m0 + mi * 16 + rr0);
                int col = n0 + ni * 16 + rl;
#pragma unroll
                for (int r = 0; r < 4; ++r)
                    out[(mrow + r) * G_ + col] = f2h(d[r]);
            }
    }
}

// ---- dual-job scan v12: 128 WGs = 2 jobs x 64 batch, 512 thr ----
// wave w: lanes = 32 j (w*32 + jl) x 2 kh. Thread (j,kh) owns k2-range
// [kh*64, kh*64+64): 46 blocks VGPR + 18 LDS (CU-resident, zero per-step
// weight memory traffic). k-reduce = permlane32_swap; h parity dbuf in LDS;
// ONE barrier/step; all-lane epilogue (c replicated).
struct ScanJob {
    const _Float16* xg;      // [64][Tc][1024] f16
    const uint4*    Wp;      // [128][256]
    const float*    bias;    // [1024]
    float*          state;   // h[64][256], c[64][256]
    void*           h_out;   // f16 (houth=1) or fp32
    float*          hc_last; // may be null
    int Tc;                  // 0 = inactive
    int toff;                // h_out time offset
    int TS;                  // h_out time stride
    int houth;               // 1 = f16 h_out
    int first;               // 1 = zero-init state
};

__global__ __launch_bounds__(512, 2) void lstm_scan2(ScanJob JA, ScanJob JB)
{
    const ScanJob J = (blockIdx.x >= 64) ? JB : JA;
    if (J.Tc == 0) return;
    const int b    = blockIdx.x & 63;
    const int tid  = threadIdx.x;
    const int w    = tid >> 6;
    const int lane = tid & 63;
    const int kh   = lane >> 5;          // k-half
    const int jl   = lane & 31;
    const int j    = w * 32 + jl;        // hidden unit (0..255)

    __shared__ __align__(16) uint4    wl[NLD][512];    // 147456 B
    __shared__ __align__(16) _Float16 hf2[2][256];     //   1024 B

    // ---- weight residency: k2 = kh*64 + p ----
    const uint4* wpb = J.Wp + (size_t)(kh * 64) * 256 + j;
    uint4 wr[NRG];
#pragma unroll
    for (int p = 0; p < NRG; ++p)
        wr[p] = wpb[(size_t)p * 256];
#pragma unroll
    for (int p = 0; p < NLD; ++p)
        wl[p][tid] = wpb[(size_t)(NRG + p) * 256];

    const int Tc    = J.Tc;
    const int houth = J.houth;
    float h = 0.f, c = 0.f;
    float bi = 0.f, bf_ = 0.f, bg = 0.f, bo = 0.f;
    const _Float16* xg = J.xg;
    size_t xo = (size_t)b * Tc * G_ + j;
    float nx0 = 0.f, nx1 = 0.f, nx2 = 0.f, nx3 = 0.f;

    if (!J.first) {                      // c,h in ALL lanes (replicated)
        h = J.state[b * H_ + j];
        c = J.state[B_ * H_ + b * H_ + j];
    }
    if (kh == 0) {
        bi  = J.bias[j];
        bf_ = J.bias[256 + j];
        bg  = J.bias[512 + j];
        bo  = J.bias[768 + j];
        hf2[0][j] = (_Float16)h;         // step 0 reads parity 0
        nx0 = (float)xg[xo];       nx1 = (float)xg[xo + 256];
        nx2 = (float)xg[xo + 512]; nx3 = (float)xg[xo + 768];
    }
    float* hof = (float*)J.h_out;
    u16*   hoh = (u16*)J.h_out;
    size_t ho = ((size_t)b * J.TS + J.toff) * H_ + j;
    __syncthreads();

    for (int t = 0; t < Tc; ++t) {
        const int par = t & 1;
        float a0, a1, a2, a3;
        if (kh == 0) {
            a0 = nx0 + bi; a1 = nx1 + bf_; a2 = nx2 + bg; a3 = nx3 + bo;
            if (t + 1 < Tc) xo += G_;            // clamped prefetch
            nx0 = (float)xg[xo];       nx1 = (float)xg[xo + 256];
            nx2 = (float)xg[xo + 512]; nx3 = (float)xg[xo + 768];
        } else {
            a0 = a1 = a2 = a3 = 0.f;
        }

        // dot over 64 k2-blocks: 46 VGPR + 18 LDS; h broadcast reads
        const uint4* hvp = ((const uint4*)hf2[par]) + kh * 16;
#pragma unroll
        for (int i = 0; i < 16; ++i) {
            uint4 hv4 = hvp[i];
            const u32* hq = &hv4.x;
#pragma unroll
            for (int q = 0; q < 4; ++q) {
                const int p = 4 * i + q;         // compile-time
                uint4 wv;
                if (p < NRG) wv = wr[p];
                else         wv = wl[p - NRG][tid];
                u32 hv = hq[q];
                a0 = dot2(wv.x, hv, a0);
                a1 = dot2(wv.y, hv, a1);
                a2 = dot2(wv.z, hv, a2);
                a3 = dot2(wv.w, hv, a3);
            }
        }

        // cross-half reduce: lane l + lane l^32 (same j, other kh)
        a0 = pl32_red(a0);
        a1 = pl32_red(a1);
        a2 = pl32_red(a2);
        a3 = pl32_red(a3);

        // epilogue in ALL lanes (c,h replicated deterministically)
        float i_ = sigm(a0);
        float f_ = sigm(a1);
        float g_ = tanh_(a2);
        float o_ = sigm(a3);
        c = f_ * c + i_ * g_;
        float hn = o_ * tanh_(c);
        h = hn;
        if (kh == 0) {
            hf2[par ^ 1][j] = (_Float16)hn;      // next step's buffer
            if (houth) hoh[ho] = f2h(hn);
            else       __builtin_nontemporal_store(hn, hof + ho);
            ho += H_;
        }
        __syncthreads();                 // hf2[par^1] visible to all waves
    }

    if (kh == 0) {
        J.state[b * H_ + j] = h;
        J.state[B_ * H_ + b * H_ + j] = c;
        if (J.hc_last) {
            J.hc_last[b * H_ + j] = h;
            J.hc_last[B_ * H_ + b * H_ + j] = c;
        }
    }
}

extern "C" void kernel_launch(void* const* d_in, const int* in_sizes, int n_in,
                              void* d_out, int out_size, void* d_ws, size_t ws_size,
                              hipStream_t stream)
{
    (void)in_sizes; (void)n_in; (void)out_size;

    const float* x    = (const float*)d_in[0];
    const float* Wih0 = (const float*)d_in[1];
    const float* Whh0 = (const float*)d_in[2];
    const float* b0   = (const float*)d_in[3];
    const float* Wih1 = (const float*)d_in[4];
    const float* Whh1 = (const float*)d_in[5];
    const float* b1   = (const float*)d_in[6];

    float* out   = (float*)d_out;
    float* hlast = out + (size_t)B_ * T_ * H_;

    // ws layout (v8)
    char* ws = (char*)d_ws;
    const size_t WPB  = (size_t)128 * 256 * 16;     // 524288 per packed W_hh
    const size_t WIHB = (size_t)1024 * 256 * 2;     // 524288 per f16 W_ih
    const size_t STB  = (size_t)2 * B_ * H_ * 4;    // 131072 per-layer state
    uint4* Wp0    = (uint4*)(ws);
    uint4* Wp1    = (uint4*)(ws + WPB);
    u16*   Wih0h  = (u16*)(ws + 2 * WPB);
    u16*   Wih1h  = (u16*)(ws + 2 * WPB + WIHB);
    float* state0 = (float*)(ws + 2 * WPB + 2 * WIHB);
    float* state1 = (float*)(ws + 2 * WPB + 2 * WIHB + STB);
    const size_t BASE = 2 * WPB + 2 * WIHB + 2 * STB;   // 2359296

    // Tc: largest power-of-2 <= 256 fitting ws.
    int Tc = 16;
    for (int tc = 256; tc >= 16; tc >>= 1)
        if (BASE + (size_t)tc * 294912 <= ws_size) { Tc = tc; break; }
    const int nch    = T_ / Tc;
    const int tclog2 = 31 - __builtin_clz((unsigned)Tc);
    const size_t H1CB = (size_t)B_ * Tc * H_ * 2;
    const size_t XGB  = (size_t)B_ * Tc * G_ * 2;
    u16*      h1c = (u16*)(ws + BASE);
    _Float16* xgA = (_Float16*)(ws + BASE + H1CB);
    _Float16* xgB = (_Float16*)(ws + BASE + H1CB + XGB);

    pack_whh<<<dim3(128, 2), 256, 0, stream>>>(Whh0, Whh1, Wp0, Wp1);
    pack_wih<<<dim3(256, 2), 256, 0, stream>>>(Wih0, Wih1, Wih0h, Wih1h);

    const int gemmWG = (B_ * Tc) / 64;

    // prologue: xg for layer-0 chunk 0
    {
        GemmJob GA = {}; GA.active = 1;
        GA.Av = x; GA.Bh = Wih0h; GA.out = (u16*)xgA;
        GA.tclog2 = tclog2; GA.Tstride = T_; GA.t0 = 0; GA.ahalf = 0;
        GemmJob GB = {}; GB.active = 0;
        gemm_xg2<<<dim3(gemmWG, 2), 256, 0, stream>>>(GA, GB);
    }

    for (int s = 0; s <= nch; ++s) {
        ScanJob JA = {}; JA.Tc = 0;
        ScanJob JB = {}; JB.Tc = 0;
        if (s < nch) {                      // layer 0, chunk s
            JA.xg = xgA;  JA.Wp = Wp0;  JA.bias = b0;  JA.state = state0;
            JA.h_out = h1c;  JA.hc_last = nullptr;
            JA.Tc = Tc;  JA.toff = 0;  JA.TS = Tc;  JA.houth = 1;
            JA.first = (s == 0);
        }
        if (s >= 1) {                       // layer 1, chunk s-1
            int cc = s - 1;
            JB.xg = xgB;  JB.Wp = Wp1;  JB.bias = b1;  JB.state = state1;
            JB.h_out = out;  JB.hc_last = (cc == nch - 1) ? hlast : nullptr;
            JB.Tc = Tc;  JB.toff = cc * Tc;  JB.TS = T_;  JB.houth = 0;
            JB.first = (cc == 0);
        }
        lstm_scan2<<<128, 512, 0, stream>>>(JA, JB);

        // fused: layer-0 gemm chunk s+1 + layer-1 gemm chunk s
        GemmJob GA = {}; GA.active = 0;
        GemmJob GB = {}; GB.active = 0;
        if (s + 1 < nch) {
            GA.active = 1; GA.Av = x; GA.Bh = Wih0h; GA.out = (u16*)xgA;
            GA.tclog2 = tclog2; GA.Tstride = T_; GA.t0 = (s + 1) * Tc; GA.ahalf = 0;
        }
        if (s < nch) {
            GB.active = 1; GB.Av = h1c; GB.Bh = Wih1h; GB.out = (u16*)xgB;
            GB.tclog2 = tclog2; GB.Tstride = Tc; GB.t0 = 0; GB.ahalf = 1;
        }
        if (GA.active || GB.active)
            gemm_xg2<<<dim3(gemmWG, 2), 256, 0, stream>>>(GA, GB);
    }
}

// Round 13
// 3921.970 us; speedup vs baseline: 11.1114x; 1.2121x over previous
//
#include <hip/hip_runtime.h>
#include <hip/hip_bf16.h>

// 2-layer LSTM, B=64 T=2048 D=H=256, fp32 I/O.
// v13 = v8 scan (byte-exact, measured best of 5 variants at 426us/slot)
//       + fused dual-gemm dispatch (v12's one validated gain, -28us total).
//   Variant ranking (us/slot): v8 426 < v9 484 < v12 517 < v11 920 < v10 5150.
//   Lessons locked in: per-step cross-WG sync dead (v10); per-step L2 weight
//   streaming dead (v11); permlane remap costs > barrier saved (v12);
//   1024-thr 4-way split hits regalloc 64V+64A (v9). Pipeline width is
//   structurally 2 (layer anti-diagonal) -> 128 CUs max for this algorithm.

typedef unsigned short u16;
typedef unsigned int   u32;

typedef __attribute__((ext_vector_type(8))) _Float16       half8;
typedef __attribute__((ext_vector_type(2))) _Float16       half2_t;
typedef __attribute__((ext_vector_type(8))) unsigned short ushort8;
typedef __attribute__((ext_vector_type(4))) float          f32x4;

#define B_  64
#define T_  2048
#define D_  256
#define H_  256
#define G_  1024   // 4*H

#define NRG 46     // scan: k2-blocks per thread in VGPRs
#define NLD 18     // scan: k2-blocks per thread in LDS (NRG+NLD = 64)
static_assert(NRG + NLD == 64, "k-split coverage");

// ---- helpers ----
__device__ __forceinline__ u16 f2h(float f) {           // RNE fp32->fp16
    union { _Float16 h; u16 b; } v; v.h = (_Float16)f; return v.b;
}
__device__ __forceinline__ float dot2(u32 w, u32 hv, float acc) {
#if __has_builtin(__builtin_amdgcn_fdot2)
    union { u32 u; half2_t h; } a, b;
    a.u = w; b.u = hv;
    return __builtin_amdgcn_fdot2(a.h, b.h, acc, false);
#else
    union { u32 u; _Float16 h[2]; } a, b;
    a.u = w; b.u = hv;
    acc += (float)a.h[0] * (float)b.h[0];
    acc += (float)a.h[1] * (float)b.h[1];
    return acc;
#endif
}
__device__ __forceinline__ float sigm(float x) {
    return 1.0f / (1.0f + __expf(-x));
}
__device__ __forceinline__ float tanh_(float x) {
    float e = __expf(-2.0f * fabsf(x));
    float r = (1.0f - e) / (1.0f + e);
    return x < 0.0f ? -r : r;
}

// ---- pack W_hh [1024][256] fp32 -> Wp[k2][j] = uint4{i,f,g,o} f16-pairs --
__global__ __launch_bounds__(256) void pack_whh(
    const float* __restrict__ W0, const float* __restrict__ W1,
    uint4* __restrict__ P0, uint4* __restrict__ P1)
{
    const int k2 = blockIdx.x;          // 0..127
    const int j  = threadIdx.x;         // 0..255
    const float* W = blockIdx.y ? W1 : W0;
    uint4*       P = blockIdx.y ? P1 : P0;
    uint4 v;
    u32* vp = &v.x;
#pragma unroll
    for (int g = 0; g < 4; ++g) {
        float2 w = *(const float2*)(W + (size_t)(g * 256 + j) * 256 + 2 * k2);
        vp[g] = (u32)f2h(w.x) | ((u32)f2h(w.y) << 16);
    }
    P[(size_t)k2 * 256 + j] = v;
}

// ---- pack W_ih [1024][256] fp32 -> f16 row-major (both layers) ----
__global__ __launch_bounds__(256) void pack_wih(
    const float* __restrict__ W0, const float* __restrict__ W1,
    u16* __restrict__ O0, u16* __restrict__ O1)
{
    const float* W = blockIdx.y ? W1 : W0;
    u16*         O = blockIdx.y ? O1 : O0;
    size_t i = (size_t)blockIdx.x * 256 + threadIdx.x;   // over 65536 float4
    float4 v = ((const float4*)W)[i];
    u32 lo = (u32)f2h(v.x) | ((u32)f2h(v.y) << 16);
    u32 hi = (u32)f2h(v.z) | ((u32)f2h(v.w) << 16);
    uint2 u; u.x = lo; u.y = hi;
    ((uint2*)O)[i] = u;
}

// ---- fused dual xg GEMM: blockIdx.y selects job; f16 MFMA ----
// Per job: one WG per 64-row M-tile, A staged once in LDS f16, full N loop.
struct GemmJob {
    const void* Av;      // fp32 (ahalf=0) or f16 (ahalf=1)
    const u16*  Bh;      // [1024][256] f16
    u16*        out;     // [B*Tc][1024] f16
    int tclog2, Tstride, t0, ahalf, active;
};

__global__ __launch_bounds__(256) void gemm_xg2(GemmJob GA, GemmJob GB)
{
    const GemmJob G = blockIdx.y ? GB : GA;
    if (!G.active) return;
    __shared__ __align__(16) u16 As[64][264];   // 33792 B
    const int tid    = threadIdx.x;
    const int m0     = blockIdx.x * 64;
    const int tcmask = (1 << G.tclog2) - 1;

    if (G.ahalf) {
        const u16* Ah = (const u16*)G.Av;
#pragma unroll
        for (int it = 0; it < 8; ++it) {
            int idx = it * 256 + tid;            // 2048 = 64 rows x 32 u16x8
            int row = idx >> 5;
            int c8  = idx & 31;
            int m   = m0 + row;
            size_t grow = (size_t)(m >> G.tclog2) * G.Tstride + G.t0 + (m & tcmask);
            ushort8 v = *(const ushort8*)(Ah + grow * D_ + c8 * 8);
            *(ushort8*)(&As[row][c8 * 8]) = v;
        }
    } else {
        const float* Af = (const float*)G.Av;
#pragma unroll
        for (int it = 0; it < 16; ++it) {
            int idx = it * 256 + tid;            // 4096 = 64 rows x 64 f32x4
            int row = idx >> 6;
            int c4  = idx & 63;
            int m   = m0 + row;
            size_t grow = (size_t)(m >> G.tclog2) * G.Tstride + G.t0 + (m & tcmask);
            float4 v = *(const float4*)(Af + grow * D_ + c4 * 4);
            uint2 u;
            u.x = (u32)f2h(v.x) | ((u32)f2h(v.y) << 16);
            u.y = (u32)f2h(v.z) | ((u32)f2h(v.w) << 16);
            *(uint2*)(&As[row][c4 * 4]) = u;
        }
    }
    __syncthreads();

    const int l   = tid & 63;
    const int w   = tid >> 6;
    const int rl  = l & 15;
    const int kg  = l >> 4;
    const int rr0 = kg * 4;
    u16* out = G.out;

    for (int nb = 0; nb < 8; ++nb) {
        const int n0 = nb * 128 + w * 32;
        f32x4 zz = {0.f, 0.f, 0.f, 0.f};
        f32x4 acc[4][2];
#pragma unroll
        for (int mi = 0; mi < 4; ++mi)
#pragma unroll
            for (int ni = 0; ni < 2; ++ni) acc[mi][ni] = zz;

#pragma unroll
        for (int ks = 0; ks < 8; ++ks) {
            const int k = ks * 32 + kg * 8;
            half8 a[4], bb[2];
#pragma unroll
            for (int mi = 0; mi < 4; ++mi)
                a[mi] = *(const half8*)(&As[mi * 16 + rl][k]);
#pragma unroll
            for (int ni = 0; ni < 2; ++ni)
                bb[ni] = *(const half8*)(G.Bh + (size_t)(n0 + ni * 16 + rl) * D_ + k);
#pragma unroll
            for (int mi = 0; mi < 4; ++mi)
#pragma unroll
                for (int ni = 0; ni < 2; ++ni)
                    acc[mi][ni] = __builtin_amdgcn_mfma_f32_16x16x32_f16(
                        a[mi], bb[ni], acc[mi][ni], 0, 0, 0);
        }

        // C/D layout: col = lane&15, row = (lane>>4)*4 + reg
#pragma unroll
        for (int mi = 0; mi < 4; ++mi)
#pragma unroll
            for (int ni = 0; ni < 2; ++ni) {
                f32x4 d = acc[mi][ni];
                size_t mrow = (size_t)(m0 + mi * 16 + rr0);
                int col = n0 + ni * 16 + rl;
#pragma unroll
                for (int r = 0; r < 4; ++r)
                    out[(mrow + r) * G_ + col] = f2h(d[r]);
            }
    }
}

// ---- dual-job sequential scan (v8 EXACT): 128 WGs = 2 jobs x 64 batch ----
// thread (j, kh): hidden unit j = tid&255, k2-half kh = tid>>8 (64 blocks:
// 46 VGPR + 18 LDS). h broadcast as f16 pairs in LDS (wave-uniform reads);
// partial gate sums via float4 red[] + barrier; kh0 does epilogue.
struct ScanJob {
    const _Float16* xg;      // [64][Tc][1024] f16
    const uint4*    Wp;      // [128][256]
    const float*    bias;    // [1024]
    float*          state;   // h[64][256], c[64][256]
    void*           h_out;   // f16 (houth=1) or fp32
    float*          hc_last; // may be null
    int Tc;                  // 0 = inactive
    int toff;                // h_out time offset
    int TS;                  // h_out time stride
    int houth;               // 1 = f16 h_out
    int first;               // 1 = zero-init state
};

__global__ __launch_bounds__(512, 2) void lstm_scan2(ScanJob JA, ScanJob JB)
{
    const ScanJob J = (blockIdx.x >= 64) ? JB : JA;
    if (J.Tc == 0) return;
    const int b   = blockIdx.x & 63;
    const int tid = threadIdx.x;
    const int j   = tid & 255;
    const int kh  = tid >> 8;

    __shared__ __align__(16) uint4  wl[NLD][512];   // 147456 B
    __shared__ __align__(16) u32    hf_p[128];      //    512 B (f16 pairs)
    __shared__ __align__(16) float4 red[256];       //   4096 B

    // ---- one-time weight residency (per thread: k2 = kh*64 + p) ----
    const uint4* wpb = J.Wp + (size_t)(kh * 64) * 256 + j;
    uint4 wr[NRG];
#pragma unroll
    for (int p = 0; p < NRG; ++p)
        wr[p] = wpb[(size_t)p * 256];
#pragma unroll
    for (int p = 0; p < NLD; ++p)
        wl[p][tid] = wpb[(size_t)(NRG + p) * 256];

    const int Tc = J.Tc;
    const int houth = J.houth;
    float h = 0.f, c = 0.f;
    float bi = 0.f, bf_ = 0.f, bg = 0.f, bo = 0.f;
    const _Float16* xg = J.xg;
    size_t xo = (size_t)b * Tc * G_ + j;
    float nx0 = 0.f, nx1 = 0.f, nx2 = 0.f, nx3 = 0.f;
    _Float16* hfh = (_Float16*)hf_p;

    if (kh == 0) {
        if (!J.first) {
            h = J.state[b * H_ + j];
            c = J.state[B_ * H_ + b * H_ + j];
        }
        bi  = J.bias[j];
        bf_ = J.bias[256 + j];
        bg  = J.bias[512 + j];
        bo  = J.bias[768 + j];
        hfh[j] = (_Float16)h;
        nx0 = (float)xg[xo];       nx1 = (float)xg[xo + 256];
        nx2 = (float)xg[xo + 512]; nx3 = (float)xg[xo + 768];
    }
    const uint4* hv4p = ((const uint4*)hf_p) + kh * 16;  // 16 uint4 = 64 k2
    float* hof = (float*)J.h_out;
    u16*   hoh = (u16*)J.h_out;
    size_t ho = ((size_t)b * J.TS + J.toff) * H_ + j;
    __syncthreads();

    for (int t = 0; t < Tc; ++t) {
        float a0, a1, a2, a3;
        if (kh == 0) {
            a0 = nx0 + bi; a1 = nx1 + bf_; a2 = nx2 + bg; a3 = nx3 + bo;
            if (t + 1 < Tc) xo += G_;            // clamped prefetch
            nx0 = (float)xg[xo];       nx1 = (float)xg[xo + 256];
            nx2 = (float)xg[xo + 512]; nx3 = (float)xg[xo + 768];
        } else {
            a0 = a1 = a2 = a3 = 0.f;
        }

        // dot over this thread's 64 k2-blocks (4 per hv uint4)
#pragma unroll
        for (int i = 0; i < 16; ++i) {
            uint4 hv4 = hv4p[i];                 // broadcast read
            const u32* hq = &hv4.x;
#pragma unroll
            for (int q = 0; q < 4; ++q) {
                const int p = 4 * i + q;         // compile-time
                uint4 wv;
                if (p < NRG) wv = wr[p];
                else         wv = wl[p - NRG][tid];
                u32 hv = hq[q];
                a0 = dot2(wv.x, hv, a0);
                a1 = dot2(wv.y, hv, a1);
                a2 = dot2(wv.z, hv, a2);
                a3 = dot2(wv.w, hv, a3);
            }
        }

        if (kh == 1) {
            float4 r4; r4.x = a0; r4.y = a1; r4.z = a2; r4.w = a3;
            red[j] = r4;
        }
        __syncthreads();   // partials visible; all hv reads of step done
        if (kh == 0) {
            float4 r4 = red[j];
            a0 += r4.x; a1 += r4.y; a2 += r4.z; a3 += r4.w;
            float i_ = sigm(a0);
            float f_ = sigm(a1);
            float g_ = tanh_(a2);
            float o_ = sigm(a3);
            c = f_ * c + i_ * g_;
            float hn = o_ * tanh_(c);
            h = hn;
            hfh[j] = (_Float16)hn;
            if (houth) hoh[ho] = f2h(hn);
            else       __builtin_nontemporal_store(hn, hof + ho);
            ho += H_;
        }
        __syncthreads();   // new h visible
    }

    if (kh == 0) {
        J.state[b * H_ + j] = h;
        J.state[B_ * H_ + b * H_ + j] = c;
        if (J.hc_last) {
            J.hc_last[b * H_ + j] = h;
            J.hc_last[B_ * H_ + b * H_ + j] = c;
        }
    }
}

extern "C" void kernel_launch(void* const* d_in, const int* in_sizes, int n_in,
                              void* d_out, int out_size, void* d_ws, size_t ws_size,
                              hipStream_t stream)
{
    (void)in_sizes; (void)n_in; (void)out_size;

    const float* x    = (const float*)d_in[0];
    const float* Wih0 = (const float*)d_in[1];
    const float* Whh0 = (const float*)d_in[2];
    const float* b0   = (const float*)d_in[3];
    const float* Wih1 = (const float*)d_in[4];
    const float* Whh1 = (const float*)d_in[5];
    const float* b1   = (const float*)d_in[6];

    float* out   = (float*)d_out;
    float* hlast = out + (size_t)B_ * T_ * H_;

    // ws layout (v8)
    char* ws = (char*)d_ws;
    const size_t WPB  = (size_t)128 * 256 * 16;     // 524288 per packed W_hh
    const size_t WIHB = (size_t)1024 * 256 * 2;     // 524288 per f16 W_ih
    const size_t STB  = (size_t)2 * B_ * H_ * 4;    // 131072 per-layer state
    uint4* Wp0    = (uint4*)(ws);
    uint4* Wp1    = (uint4*)(ws + WPB);
    u16*   Wih0h  = (u16*)(ws + 2 * WPB);
    u16*   Wih1h  = (u16*)(ws + 2 * WPB + WIHB);
    float* state0 = (float*)(ws + 2 * WPB + 2 * WIHB);
    float* state1 = (float*)(ws + 2 * WPB + 2 * WIHB + STB);
    const size_t BASE = 2 * WPB + 2 * WIHB + 2 * STB;   // 2359296

    // Tc: largest power-of-2 <= 256 fitting ws.
    // per-Tc bytes: h1c 32768 + xgA/xgB 2*131072 = 294912
    int Tc = 16;
    for (int tc = 256; tc >= 16; tc >>= 1)
        if (BASE + (size_t)tc * 294912 <= ws_size) { Tc = tc; break; }
    const int nch    = T_ / Tc;
    const int tclog2 = 31 - __builtin_clz((unsigned)Tc);
    const size_t H1CB = (size_t)B_ * Tc * H_ * 2;
    const size_t XGB  = (size_t)B_ * Tc * G_ * 2;
    u16*      h1c = (u16*)(ws + BASE);
    _Float16* xgA = (_Float16*)(ws + BASE + H1CB);
    _Float16* xgB = (_Float16*)(ws + BASE + H1CB + XGB);

    pack_whh<<<dim3(128, 2), 256, 0, stream>>>(Whh0, Whh1, Wp0, Wp1);
    pack_wih<<<dim3(256, 2), 256, 0, stream>>>(Wih0, Wih1, Wih0h, Wih1h);

    const int gemmWG = (B_ * Tc) / 64;

    // prologue: xg for layer-0 chunk 0
    {
        GemmJob GA = {}; GA.active = 1;
        GA.Av = x; GA.Bh = Wih0h; GA.out = (u16*)xgA;
        GA.tclog2 = tclog2; GA.Tstride = T_; GA.t0 = 0; GA.ahalf = 0;
        GemmJob GB = {}; GB.active = 0;
        gemm_xg2<<<dim3(gemmWG, 2), 256, 0, stream>>>(GA, GB);
    }

    for (int s = 0; s <= nch; ++s) {
        ScanJob JA = {}; JA.Tc = 0;
        ScanJob JB = {}; JB.Tc = 0;
        if (s < nch) {                      // layer 0, chunk s
            JA.xg = xgA;  JA.Wp = Wp0;  JA.bias = b0;  JA.state = state0;
            JA.h_out = h1c;  JA.hc_last = nullptr;
            JA.Tc = Tc;  JA.toff = 0;  JA.TS = Tc;  JA.houth = 1;
            JA.first = (s == 0);
        }
        if (s >= 1) {                       // layer 1, chunk s-1
            int cc = s - 1;
            JB.xg = xgB;  JB.Wp = Wp1;  JB.bias = b1;  JB.state = state1;
            JB.h_out = out;  JB.hc_last = (cc == nch - 1) ? hlast : nullptr;
            JB.Tc = Tc;  JB.toff = cc * Tc;  JB.TS = T_;  JB.houth = 0;
            JB.first = (cc == 0);
        }
        lstm_scan2<<<128, 512, 0, stream>>>(JA, JB);

        // fused: layer-0 gemm chunk s+1 + layer-1 gemm chunk s
        GemmJob GA = {}; GA.active = 0;
        GemmJob GB = {}; GB.active = 0;
        if (s + 1 < nch) {
            GA.active = 1; GA.Av = x; GA.Bh = Wih0h; GA.out = (u16*)xgA;
            GA.tclog2 = tclog2; GA.Tstride = T_; GA.t0 = (s + 1) * Tc; GA.ahalf = 0;
        }
        if (s < nch) {
            GB.active = 1; GB.Av = h1c; GB.Bh = Wih1h; GB.out = (u16*)xgB;
            GB.tclog2 = tclog2; GB.Tstride = Tc; GB.t0 = 0; GB.ahalf = 1;
        }
        if (GA.active || GB.active)
            gemm_xg2<<<dim3(gemmWG, 2), 256, 0, stream>>>(GA, GB);
    }
}